// Round 2
// baseline (355.736 us; speedup 1.0000x reference)
//
#include <hip/hip_runtime.h>

#define B_TOTAL 4096
#define D 32
#define H 256
#define TPS 16            // lanes per sample
#define HPT (H / TPS)     // hidden units per lane = 16
#define SPB (256 / TPS)   // samples per block = 16
#define LSTR 36           // LDS row stride (floats): 16B-aligned, 2-way-bank-only

static constexpr float EPS = 0.1f;

// One ODE eval: given xc[32] (replicated across the sample's 16 lanes),
// produce full grad g[32] (replicated after reduce) and laplacian.
__device__ __forceinline__ void eval_one(
    const float* __restrict__ w1L, int t,
    const float b1r[HPT], const float w2r[HPT], const float cr[HPT],
    const float xc[D], float g[D], float& lap_out)
{
  // z-pass: z_h = b1_h + sum_d w1[d,h] * xc[d], for h = t + 16*j
  float z[HPT];
#pragma unroll
  for (int j = 0; j < HPT; ++j) z[j] = b1r[j];
#pragma unroll
  for (int j = 0; j < HPT; ++j) {
    const float* row = w1L + (t + TPS * j) * LSTR;
#pragma unroll
    for (int q = 0; q < D / 4; ++q) {
      float4 w = *reinterpret_cast<const float4*>(row + 4 * q);
      z[j] = fmaf(w.x, xc[4*q+0], z[j]);
      z[j] = fmaf(w.y, xc[4*q+1], z[j]);
      z[j] = fmaf(w.z, xc[4*q+2], z[j]);
      z[j] = fmaf(w.w, xc[4*q+3], z[j]);
    }
  }

  // activation: s = sigmoid(z); a = s*w2; lap += s(1-s)*w2*c
  float a[HPT];
  float lap = 0.0f;
#pragma unroll
  for (int j = 0; j < HPT; ++j) {
    float e = __expf(-z[j]);
    float s = __builtin_amdgcn_rcpf(1.0f + e);
    float av = s * w2r[j];
    a[j] = av;
    lap = fmaf(av * (1.0f - s), cr[j], lap);
  }

  // grad-pass: g[d] = sum_h a_h * w1[d,h]  (partial over this lane's h's)
#pragma unroll
  for (int d = 0; d < D; ++d) g[d] = 0.0f;
#pragma unroll
  for (int j = 0; j < HPT; ++j) {
    const float* row = w1L + (t + TPS * j) * LSTR;
#pragma unroll
    for (int q = 0; q < D / 4; ++q) {
      float4 w = *reinterpret_cast<const float4*>(row + 4 * q);
      g[4*q+0] = fmaf(a[j], w.x, g[4*q+0]);
      g[4*q+1] = fmaf(a[j], w.y, g[4*q+1]);
      g[4*q+2] = fmaf(a[j], w.z, g[4*q+2]);
      g[4*q+3] = fmaf(a[j], w.w, g[4*q+3]);
    }
  }

  // reduce across the 16 lanes of this sample (lanes are contiguous, masks<16)
#pragma unroll
  for (int mask = 1; mask < TPS; mask <<= 1) {
    lap += __shfl_xor(lap, mask);
#pragma unroll
    for (int d = 0; d < D; ++d) g[d] += __shfl_xor(g[d], mask);
  }
  lap_out = lap;
}

__global__ __launch_bounds__(256, 1) void ma_flow_kernel(
    const float* __restrict__ x_in, const float* __restrict__ logp_in,
    const float* __restrict__ w1, const float* __restrict__ b1,
    const float* __restrict__ w2, float* __restrict__ out)
{
  __shared__ __align__(16) float w1L[H * LSTR];
  __shared__ float cL[H];

  const int tid = threadIdx.x;

  // Stage w1 transposed into LDS: w1L[h][d], h = tid (blockDim == H == 256).
  // Also compute c_h = sum_d w1[d,h]^2 on the fly.
  {
    float csum = 0.0f;
#pragma unroll
    for (int d = 0; d < D; ++d) {
      float v = w1[d * H + tid];           // coalesced across tid
      w1L[tid * LSTR + d] = v;
      csum = fmaf(v, v, csum);
    }
    cL[tid] = csum;
  }
  __syncthreads();

  const int t = tid & (TPS - 1);                       // h-lane within sample
  const int sample = blockIdx.x * SPB + (tid >> 4);    // 16 samples / block

  // per-lane h-set: h = t + 16*j  (stride-16 interleave => distinct LDS banks)
  float b1r[HPT], w2r[HPT], cr[HPT];
#pragma unroll
  for (int j = 0; j < HPT; ++j) {
    int h = t + TPS * j;
    b1r[j] = b1[h];
    w2r[j] = w2[h];
    cr[j] = cL[h];
  }

  // load x (replicated across the sample's 16 lanes), vectorized
  float x0[D];
#pragma unroll
  for (int q = 0; q < D / 4; ++q) {
    float4 v = *reinterpret_cast<const float4*>(x_in + sample * D + 4 * q);
    x0[4*q+0] = v.x; x0[4*q+1] = v.y; x0[4*q+2] = v.z; x0[4*q+3] = v.w;
  }
  float lp = logp_in[sample];

  float xa[D], xc[D];
#pragma unroll
  for (int d = 0; d < D; ++d) xc[d] = x0[d];

  // 2 RK4 steps x 4 stages; single eval instance (I-cache friendly)
#pragma unroll 1
  for (int step = 0; step < 2; ++step) {
#pragma unroll 1
    for (int st = 0; st < 4; ++st) {
      float g[D]; float lap;
      eval_one(w1L, t, b1r, w2r, cr, xc, g, lap);

      const float wa = (st == 0 || st == 3) ? (EPS / 6.0f) : (EPS / 3.0f);
      if (st == 0) {
#pragma unroll
        for (int d = 0; d < D; ++d) xa[d] = fmaf(wa, g[d], x0[d]);
      } else {
#pragma unroll
        for (int d = 0; d < D; ++d) xa[d] = fmaf(wa, g[d], xa[d]);
      }
      lp = fmaf(-wa, lap, lp);   // dlogp/dt = -eps*lap

      if (st < 3) {
        const float wc = (st == 2) ? EPS : (EPS * 0.5f);
#pragma unroll
        for (int d = 0; d < D; ++d) xc[d] = fmaf(wc, g[d], x0[d]);
      } else {
#pragma unroll
        for (int d = 0; d < D; ++d) { x0[d] = xa[d]; xc[d] = xa[d]; }
      }
    }
  }

  // write back: lane t==0 of each sample owns the full replicated state
  if (t == 0) {
#pragma unroll
    for (int q = 0; q < D / 4; ++q) {
      float4 v;
      v.x = x0[4*q+0]; v.y = x0[4*q+1]; v.z = x0[4*q+2]; v.w = x0[4*q+3];
      *reinterpret_cast<float4*>(out + sample * D + 4 * q) = v;
    }
    out[B_TOTAL * D + sample] = lp;   // logp concatenated after x
  }
}

extern "C" void kernel_launch(void* const* d_in, const int* in_sizes, int n_in,
                              void* d_out, int out_size, void* d_ws, size_t ws_size,
                              hipStream_t stream) {
  const float* x    = (const float*)d_in[0];
  const float* logp = (const float*)d_in[1];
  const float* w1   = (const float*)d_in[2];
  const float* b1   = (const float*)d_in[3];
  const float* w2   = (const float*)d_in[4];
  // d_in[5] (b2) shifts u only; it does not affect grad_u or the laplacian.
  float* out = (float*)d_out;

  ma_flow_kernel<<<B_TOTAL / SPB, 256, 0, stream>>>(x, logp, w1, b1, w2, out);
}

// Round 3
// 41.652 us; speedup vs baseline: 8.5407x; 8.5407x over previous
//
#include <hip/hip_runtime.h>

#define B_TOTAL 4096
#define D 32
#define H 256
#define TPS 16            // lanes per sample
#define HPT (H / TPS)     // hidden units per lane = 16
#define SPB (256 / TPS)   // samples per block = 16
#define LSTR 36           // LDS row stride (floats): 16B-aligned; interleaved h-sets -> 2-way banks only

static constexpr float EPS = 0.1f;

__global__ __launch_bounds__(256, 1) void ma_flow_kernel(
    const float* __restrict__ x_in, const float* __restrict__ logp_in,
    const float* __restrict__ w1, const float* __restrict__ b1,
    const float* __restrict__ w2, float* __restrict__ out)
{
  __shared__ __align__(16) float w1L[H * LSTR];   // w1 transposed: [h][d]
  __shared__ __align__(16) float4 hcons[H];       // (b1[h], w2[h], w2[h]*c[h], 0)

  const int tid = threadIdx.x;

  // Stage w1 transposed into LDS (blockDim == H == 256: thread tid owns column h=tid).
  {
    float csum = 0.0f;
#pragma unroll
    for (int d = 0; d < D; ++d) {
      float v = w1[d * H + tid];                  // coalesced across tid
      w1L[tid * LSTR + d] = v;
      csum = fmaf(v, v, csum);                    // c_h = sum_d w1[d,h]^2
    }
    float bb = b1[tid], ww = w2[tid];
    hcons[tid] = make_float4(bb, ww, ww * csum, 0.0f);
  }
  __syncthreads();

  const int t = tid & (TPS - 1);                  // lane within sample
  const int sample = blockIdx.x * SPB + (tid >> 4);

  // Replicated state: x0 (step base) and xc (stage input). RK4 accumulator is
  // DISTRIBUTED: lane t owns dims {2t, 2t+1} in acc0/acc1 (saves 30 VGPRs).
  float x0[D], xc[D];
#pragma unroll
  for (int q = 0; q < D / 4; ++q) {
    float4 v = *reinterpret_cast<const float4*>(x_in + sample * D + 4 * q);
    x0[4*q+0] = v.x; x0[4*q+1] = v.y; x0[4*q+2] = v.z; x0[4*q+3] = v.w;
  }
#pragma unroll
  for (int d = 0; d < D; ++d) xc[d] = x0[d];
  float lp = logp_in[sample];
  float acc0 = 0.0f, acc1 = 0.0f;

#pragma unroll 1
  for (int step = 0; step < 2; ++step) {
#pragma unroll 1
    for (int st = 0; st < 4; ++st) {
      const float wa = (st == 0 || st == 3) ? (EPS / 6.0f) : (EPS / 3.0f);
      const float wc = (st == 2) ? EPS : (EPS * 0.5f);

      // ---- fused eval: one pass over this lane's 16 h's (h = t + 16*j) ----
      float g[D];
#pragma unroll
      for (int d = 0; d < D; ++d) g[d] = 0.0f;
      float lap = 0.0f;

#pragma unroll 2
      for (int j = 0; j < HPT; ++j) {
        const float* row = w1L + (t + TPS * j) * LSTR;
        const float4 hc = hcons[t + TPS * j];
        float wreg[D];
        float z = hc.x;
#pragma unroll
        for (int q = 0; q < D / 4; ++q) {
          float4 w = *reinterpret_cast<const float4*>(row + 4 * q);
          wreg[4*q+0] = w.x; wreg[4*q+1] = w.y;
          wreg[4*q+2] = w.z; wreg[4*q+3] = w.w;
          z = fmaf(w.x, xc[4*q+0], z);
          z = fmaf(w.y, xc[4*q+1], z);
          z = fmaf(w.z, xc[4*q+2], z);
          z = fmaf(w.w, xc[4*q+3], z);
        }
        float e = __expf(-z);
        float s = __builtin_amdgcn_rcpf(1.0f + e);  // sigmoid
        float a = s * hc.y;                          // s * w2
        lap = fmaf(s * (1.0f - s), hc.z, lap);       // s(1-s) * w2*c
#pragma unroll
        for (int d = 0; d < D; ++d) g[d] = fmaf(a, wreg[d], g[d]);  // reuse row regs
      }

      // laplacian: butterfly over the sample's 16 lanes, update replicated lp
      lap += __shfl_xor(lap, 1);
      lap += __shfl_xor(lap, 2);
      lap += __shfl_xor(lap, 4);
      lap += __shfl_xor(lap, 8);
      lp = fmaf(-wa, lap, lp);

      // per-dim reduce + RK4 updates (gd replicated to all 16 lanes by butterfly)
#pragma unroll
      for (int d = 0; d < D; ++d) {
        float gd = g[d];
        gd += __shfl_xor(gd, 1);
        gd += __shfl_xor(gd, 2);
        gd += __shfl_xor(gd, 4);
        gd += __shfl_xor(gd, 8);
        const float m = (t == (d >> 1)) ? wa : 0.0f;   // owner-lane predicate
        if (d & 1) acc1 = fmaf(m, gd, acc1);
        else       acc0 = fmaf(m, gd, acc0);
        if (st < 3) xc[d] = fmaf(wc, gd, x0[d]);       // next stage input
      }

      if (st == 3) {
        // step end: x0 += accumulated delta (owner lane d>>1 holds dim d)
#pragma unroll
        for (int d = 0; d < D; ++d) {
          float av = (d & 1) ? acc1 : acc0;
          float delta = __shfl(av, d >> 1, TPS);
          x0[d] += delta;
          xc[d] = x0[d];
        }
        acc0 = 0.0f; acc1 = 0.0f;
      }
    }
  }

  // write back: lane t==0 of each sample holds the full replicated state
  if (t == 0) {
#pragma unroll
    for (int q = 0; q < D / 4; ++q) {
      float4 v;
      v.x = x0[4*q+0]; v.y = x0[4*q+1]; v.z = x0[4*q+2]; v.w = x0[4*q+3];
      *reinterpret_cast<float4*>(out + sample * D + 4 * q) = v;
    }
    out[B_TOTAL * D + sample] = lp;   // logp concatenated after x
  }
}

extern "C" void kernel_launch(void* const* d_in, const int* in_sizes, int n_in,
                              void* d_out, int out_size, void* d_ws, size_t ws_size,
                              hipStream_t stream) {
  const float* x    = (const float*)d_in[0];
  const float* logp = (const float*)d_in[1];
  const float* w1   = (const float*)d_in[2];
  const float* b1   = (const float*)d_in[3];
  const float* w2   = (const float*)d_in[4];
  // d_in[5] (b2) shifts u only; it does not affect grad_u or the laplacian.
  float* out = (float*)d_out;

  ma_flow_kernel<<<B_TOTAL / SPB, 256, 0, stream>>>(x, logp, w1, b1, w2, out);
}

// Round 4
// 23.837 us; speedup vs baseline: 14.9237x; 1.7474x over previous
//
#include <hip/hip_runtime.h>

#define B_TOTAL 4096
#define D 32
#define H 256
#define SPB 16           // samples per block (= MFMA M)
#define HPW 64           // hidden units per wave (4 waves x 64 = 256)

static constexpr float EPS = 0.1f;

typedef __attribute__((ext_vector_type(8))) short short8v;   // 8 x bf16
typedef __attribute__((ext_vector_type(4))) float f32x4;

__device__ __forceinline__ unsigned short bf16rne(float f) {
  unsigned u = __float_as_uint(f);
  u += 0x7FFFu + ((u >> 16) & 1u);           // round-to-nearest-even
  return (unsigned short)(u >> 16);
}
__device__ __forceinline__ float bf16f(unsigned short h) {
  return __uint_as_float(((unsigned)h) << 16);
}

#define MFMA16(A, Bf, C) __builtin_amdgcn_mfma_f32_16x16x32_bf16((A), (Bf), (C), 0, 0, 0)

__global__ __launch_bounds__(256, 1) void ma_flow_kernel(
    const float* __restrict__ x_in, const float* __restrict__ logp_in,
    const float* __restrict__ w1, const float* __restrict__ b1,
    const float* __restrict__ w2, float* __restrict__ out)
{
  // a-redistribution buffer (per wave), padded row 72 bf16 (144 B, 16B-aligned rows)
  __shared__ __align__(16) unsigned short aBuf[4][SPB][72];
  __shared__ float partG[4][SPB][33];           // per-wave partial g (+lap in col 32)
  __shared__ __align__(16) float xcL[SPB][36];  // stage input (row 144 B)
  __shared__ __align__(16) float x0L[SPB][36];  // step base
  __shared__ __align__(16) float accL[SPB][36]; // RK4 accumulator
  __shared__ float lpL[SPB];

  const int tid = threadIdx.x;
  const int l  = tid & 63;
  const int wv = tid >> 6;       // wave id = h-slice
  const int lr = l & 15;         // MFMA "n / m" lane index
  const int lg = l >> 4;         // MFMA k-group
  const int hbase = wv * HPW;

  // ---------------- weight fragments (registers, hi/lo bf16 split) -------------
  // z-pass: B[k=d][n=h]  (w1 as-is). lane: k = lg*8+j, n = tau*16+lr
  short8v Bzh[4], Bzl[4];
  float b1v[4], w2v[4], w2cv[4];
#pragma unroll
  for (int tau = 0; tau < 4; ++tau) {
    const int h = hbase + tau * 16 + lr;
    float cpart = 0.0f;
    short8v hi, lo;
#pragma unroll
    for (int j = 0; j < 8; ++j) {
      float w = w1[(lg * 8 + j) * H + h];
      cpart = fmaf(w, w, cpart);
      unsigned short hb = bf16rne(w);
      hi[j] = (short)hb;
      lo[j] = (short)bf16rne(w - bf16f(hb));
    }
    Bzh[tau] = hi; Bzl[tau] = lo;
    cpart += __shfl_xor(cpart, 16);            // sum over the 4 k-groups
    cpart += __shfl_xor(cpart, 32);
    b1v[tau] = b1[h];
    float w2x = w2[h];
    w2v[tau] = w2x;
    w2cv[tau] = w2x * cpart;                   // w2[h] * sum_d w1[d,h]^2
  }
  // g-pass: B[k=h][n=d]  (w1 transposed). lane: k = kp*32+lg*8+j, n = nu*16+lr
  short8v Bgh[2][2], Bgl[2][2];
#pragma unroll
  for (int nu = 0; nu < 2; ++nu)
#pragma unroll
    for (int kp = 0; kp < 2; ++kp) {
      const int d = nu * 16 + lr;
      const float* p = w1 + d * H + (hbase + kp * 32 + lg * 8);
      short8v hi, lo;
#pragma unroll
      for (int j = 0; j < 8; ++j) {
        float w = p[j];
        unsigned short hb = bf16rne(w);
        hi[j] = (short)hb;
        lo[j] = (short)bf16rne(w - bf16f(hb));
      }
      Bgh[nu][kp] = hi; Bgl[nu][kp] = lo;
    }

  // ---------------- state init -------------------------------------------------
  for (int i = tid; i < SPB * D; i += 256) {
    int s = i >> 5, d = i & 31;
    float v = x_in[blockIdx.x * SPB * D + i];
    x0L[s][d] = v; xcL[s][d] = v; accL[s][d] = 0.0f;
  }
  if (tid < SPB) lpL[tid] = logp_in[blockIdx.x * SPB + tid];
  __syncthreads();

  // ---------------- 8 RK4 stage evaluations ------------------------------------
#pragma unroll 1
  for (int stage = 0; stage < 8; ++stage) {
    const int st = stage & 3;
    const float wa = (st == 0 || st == 3) ? (EPS / 6.0f) : (EPS / 3.0f);
    const float wc = (st == 2) ? EPS : (EPS * 0.5f);

    // -- phase 1: A-frag(xc) hi/lo, z-MFMAs, sigmoid, a-write ------------------
    const float4* xp = reinterpret_cast<const float4*>(&xcL[lr][lg * 8]);
    float4 xa4 = xp[0], xb4 = xp[1];
    float xv[8] = {xa4.x, xa4.y, xa4.z, xa4.w, xb4.x, xb4.y, xb4.z, xb4.w};
    short8v ahi, alo;
#pragma unroll
    for (int j = 0; j < 8; ++j) {
      unsigned short hb = bf16rne(xv[j]);
      ahi[j] = (short)hb;
      alo[j] = (short)bf16rne(xv[j] - bf16f(hb));
    }

    float lapp[4] = {0.0f, 0.0f, 0.0f, 0.0f};
#pragma unroll
    for (int tau = 0; tau < 4; ++tau) {
      f32x4 z = {b1v[tau], b1v[tau], b1v[tau], b1v[tau]};
      z = MFMA16(ahi, Bzh[tau], z);
      z = MFMA16(alo, Bzh[tau], z);
      z = MFMA16(ahi, Bzl[tau], z);
#pragma unroll
      for (int r = 0; r < 4; ++r) {
        float e = __expf(-z[r]);
        float s = __builtin_amdgcn_rcpf(1.0f + e);           // sigmoid
        lapp[r] = fmaf(s * (1.0f - s), w2cv[tau], lapp[r]);  // laplacian partial
        aBuf[wv][lg * 4 + r][tau * 16 + lr] = bf16rne(s * w2v[tau]);
      }
    }
    __syncthreads();

    // -- phase 2: A-frag(a), g-MFMAs, partial writes ---------------------------
    short8v aF0 = *reinterpret_cast<const short8v*>(&aBuf[wv][lr][lg * 8]);
    short8v aF1 = *reinterpret_cast<const short8v*>(&aBuf[wv][lr][32 + lg * 8]);
#pragma unroll
    for (int nu = 0; nu < 2; ++nu) {
      f32x4 g = {0.0f, 0.0f, 0.0f, 0.0f};
      g = MFMA16(aF0, Bgh[nu][0], g);
      g = MFMA16(aF0, Bgl[nu][0], g);
      g = MFMA16(aF1, Bgh[nu][1], g);
      g = MFMA16(aF1, Bgl[nu][1], g);
#pragma unroll
      for (int r = 0; r < 4; ++r)
        partG[wv][lg * 4 + r][nu * 16 + lr] = g[r];
    }
    // laplacian: reduce over the 16 h-columns (lanes lr), write col 32
#pragma unroll
    for (int m = 1; m < 16; m <<= 1)
#pragma unroll
      for (int r = 0; r < 4; ++r) lapp[r] += __shfl_xor(lapp[r], m);
    if (lr == 0) {
#pragma unroll
      for (int r = 0; r < 4; ++r) partG[wv][lg * 4 + r][32] = lapp[r];
    }
    __syncthreads();

    // -- phase 3: cross-wave reduce + RK4 state update -------------------------
    for (int i = tid; i < SPB * 33; i += 256) {
      int s = i / 33, d = i - s * 33;
      float g = partG[0][s][d] + partG[1][s][d] + partG[2][s][d] + partG[3][s][d];
      if (d < 32) {
        float acc = fmaf(wa, g, accL[s][d]);
        if (st < 3) {
          accL[s][d] = acc;
          xcL[s][d] = fmaf(wc, g, x0L[s][d]);
        } else {
          float nx = x0L[s][d] + acc;
          x0L[s][d] = nx; xcL[s][d] = nx; accL[s][d] = 0.0f;
        }
      } else {
        lpL[s] = fmaf(-wa, g, lpL[s]);   // dlogp = -eps*lap (eps folded in wa)
      }
    }
    __syncthreads();
  }

  // ---------------- output ------------------------------------------------------
  for (int i = tid; i < SPB * D; i += 256) {
    int s = i >> 5, d = i & 31;
    out[blockIdx.x * SPB * D + i] = x0L[s][d];
  }
  if (tid < SPB) out[B_TOTAL * D + blockIdx.x * SPB + tid] = lpL[tid];
}

extern "C" void kernel_launch(void* const* d_in, const int* in_sizes, int n_in,
                              void* d_out, int out_size, void* d_ws, size_t ws_size,
                              hipStream_t stream) {
  const float* x    = (const float*)d_in[0];
  const float* logp = (const float*)d_in[1];
  const float* w1   = (const float*)d_in[2];
  const float* b1   = (const float*)d_in[3];
  const float* w2   = (const float*)d_in[4];
  // d_in[5] (b2) shifts u only; it does not affect grad_u or the laplacian.
  float* out = (float*)d_out;

  ma_flow_kernel<<<B_TOTAL / SPB, 256, 0, stream>>>(x, logp, w1, b1, w2, out);
}